// Round 5
// baseline (118.377 us; speedup 1.0000x reference)
//
#include <hip/hip_runtime.h>
#include <math.h>

#define NA 5
#define NC 20
#define NH 38
#define NW 38
#define MAX_BOXES 50
#define SPAT (NH * NW)            // 1444
#define CELLS_PER_B (NA * SPAT)   // 7220
#define TPB 256                   // threads per block (4 waves)
#define CELLS_PER_T 2
#define CPB (TPB * CELLS_PER_T)   // 512 cells per block
#define GX ((CELLS_PER_B + CPB - 1) / CPB)  // 15
#define OBJECT_SCALE 5.0f
#define NOOBJECT_SCALE 1.0f

__constant__ float c_aw[NA]  = {1.3221f, 3.19275f, 5.05587f, 9.47112f, 11.2364f};
__constant__ float c_ah[NA]  = {1.73145f, 4.00944f, 8.09892f, 4.84053f, 10.0071f};
__constant__ float c_iaw[NA] = {1.f/1.3221f, 1.f/3.19275f, 1.f/5.05587f, 1.f/9.47112f, 1.f/11.2364f};
__constant__ float c_iah[NA] = {1.f/1.73145f, 1.f/4.00944f, 1.f/8.09892f, 1.f/4.84053f, 1.f/10.0071f};

// fast transcendentals: v_exp/v_log/v_rcp — loss threshold is 1.1e4
__device__ __forceinline__ float fexp(float v) { return __expf(v); }
__device__ __forceinline__ float flog(float v) { return __logf(v); }
__device__ __forceinline__ float frcp(float v) { return __builtin_amdgcn_rcpf(v); }
__device__ __forceinline__ float fsig(float v) { return frcp(1.f + __expf(-v)); }

__device__ __forceinline__ float iou_fast(float x1, float y1, float w1, float h1,
                                          float x2, float y2, float w2, float h2) {
  float uw = fmaxf(x1 + w1 * 0.5f, x2 + w2 * 0.5f) - fminf(x1 - w1 * 0.5f, x2 - w2 * 0.5f);
  float uh = fmaxf(y1 + h1 * 0.5f, y2 + h2 * 0.5f) - fminf(y1 - h1 * 0.5f, y2 - h2 * 0.5f);
  float cw = w1 + w2 - uw;
  float ch = h1 + h2 - uh;
  float inter = (cw <= 0.f || ch <= 0.f) ? 0.f : cw * ch;
  return inter * frcp(w1 * h1 + w2 * h2 - inter);
}

// exact-divide IOU for the anchor argmax (tie-break safety)
__device__ __forceinline__ float iou_wh_exact(float w1, float h1, float w2, float h2) {
  float uw = fmaxf(w1 * 0.5f, w2 * 0.5f) - fminf(-w1 * 0.5f, -w2 * 0.5f);
  float uh = fmaxf(h1 * 0.5f, h2 * 0.5f) - fminf(-h1 * 0.5f, -h2 * 0.5f);
  float cw = w1 + w2 - uw;
  float ch = h1 + h2 - uh;
  float inter = (cw <= 0.f || ch <= 0.f) ? 0.f : cw * ch;
  return inter / (w1 * h1 + w2 * h2 - inter);
}

// Fused kernel. Grid (15, nB), block 256 (4 waves) -> 15 waves/CU TLP.
// Each thread owns 2 cells. Wave 0 redundantly computes the 50-box GT prep
// into LDS. NO global atomics: each block stores its partial sum to d_ws;
// a 1-block reduce kernel sums them and overwrites d_out.
__global__ __launch_bounds__(TPB) void region_loss_kernel(
    const float* __restrict__ out, const float* __restrict__ target,
    float* __restrict__ partials) {
  const int b = blockIdx.y;
  const int s0 = blockIdx.x * CPB;
  const int tid = threadIdx.x;

  __shared__ float4 sb_lo[MAX_BOXES];     // lx, hx, ly, hy
  __shared__ float  sb_ag[MAX_BOXES];     // 0.375 * gt area (0 for sentinel)
  __shared__ int s_wcnt;
  __shared__ int s_wcell[MAX_BOXES];
  __shared__ float s_wdata[MAX_BOXES][6];
  __shared__ float s_red[TPB / 64];

  // ---- issue per-thread channel loads FIRST (overlap wave-0 prep) ----
  int sC[CELLS_PER_T];
  bool ok[CELLS_PER_T];
  const float* basep[CELLS_PER_T];
  float v0[CELLS_PER_T], v1[CELLS_PER_T], v2[CELLS_PER_T], v3[CELLS_PER_T], v4[CELLS_PER_T];
  float fi[CELLS_PER_T], fj[CELLS_PER_T], paw[CELLS_PER_T], pah[CELLS_PER_T];
#pragma unroll
  for (int q = 0; q < CELLS_PER_T; ++q) {
    int s = s0 + q * TPB + tid;
    ok[q] = (s < CELLS_PER_B);
    int sc = ok[q] ? s : 0;
    sC[q] = ok[q] ? s : -1;
    unsigned a = (unsigned)sc / SPAT;
    unsigned r = (unsigned)sc - a * SPAT;
    unsigned j = r / NW, i = r - j * NW;
    fi[q] = (float)i; fj[q] = (float)j;
    paw[q] = c_aw[a]; pah[q] = c_ah[a];
    const float* bp = out + ((size_t)(b * NA + a) * 25) * SPAT + r;
    basep[q] = bp;
    v0[q] = bp[0];
    v1[q] = bp[SPAT];
    v2[q] = bp[2 * SPAT];
    v3[q] = bp[3 * SPAT];
    v4[q] = bp[4 * SPAT];
  }

  if (tid == TPB - 1) s_wcnt = 0;
  __syncthreads();

  // ---- wave 0: GT prep for batch b into LDS ----
  if (tid < 64) {
    int t = tid;
    float cls = 0.f, x = 0.f, y = 0.f, w = 0.f, h = 0.f;
    if (t < MAX_BOXES) {
      const float* tg = target + (size_t)(b * MAX_BOXES + t) * 5;
      cls = tg[0]; x = tg[1]; y = tg[2]; w = tg[3]; h = tg[4];
    }
    unsigned long long nz = __ballot(t < MAX_BOXES && x != 0.f);
    unsigned long long low = (t < 63) ? ((1ull << (t + 1)) - 1ull) : ~0ull;
    bool valid = (t < MAX_BOXES) && ((nz & low) == low);

    float gx = x * NW, gy = y * NH, gw = w * NW, gh = h * NH;

    int best = 0; float bestiou = -1.f;
#pragma unroll
    for (int a2 = 0; a2 < NA; ++a2) {
      float aiou = iou_wh_exact(gw, gh, c_aw[a2], c_ah[a2]);
      if (aiou > bestiou) { bestiou = aiou; best = a2; }
    }
    int gi = min(max((int)gx, 0), NW - 1);
    int gj = min(max((int)gy, 0), NH - 1);

    const float* pb = out + ((size_t)(b * NA + best) * 25) * SPAT + gj * NW + gi;
    float px = fsig(pb[0]) + (float)gi;
    float py = fsig(pb[SPAT]) + (float)gj;
    float pw2 = fexp(pb[2 * SPAT]) * c_aw[best];
    float ph2 = fexp(pb[3 * SPAT]) * c_ah[best];
    float iou_gt = iou_fast(gx, gy, gw, gh, px, py, pw2, ph2);

    int cell = best * SPAT + gj * NW + gi;
    unsigned long long vm = __ballot(valid);
    bool winner = valid;                     // last valid writer wins
    for (int tp = 0; tp < MAX_BOXES; ++tp) {
      int c2 = __shfl(cell, tp);
      if (tp > t && ((vm >> tp) & 1ull) && c2 == cell) winner = false;
    }

    if (t < MAX_BOXES) {
      if (valid) {
        sb_lo[t] = make_float4(gx - gw * 0.5f, gx + gw * 0.5f,
                               gy - gh * 0.5f, gy + gh * 0.5f);
        sb_ag[t] = 0.375f * (gw * gh);
      } else {
        sb_lo[t] = make_float4(1e30f, 1e30f, 1e30f, 1e30f);  // cw<0: never suppresses
        sb_ag[t] = 0.f;
      }
      if (winner && cell >= s0 && cell < s0 + CPB) {
        int k = atomicAdd(&s_wcnt, 1);   // LDS atomic, trivial
        s_wcell[k] = cell;
        s_wdata[k][0] = gx - (float)gi;
        s_wdata[k][1] = gy - (float)gj;
        s_wdata[k][2] = flog(gw * c_iaw[best]);
        s_wdata[k][3] = flog(gh * c_iah[best]);
        s_wdata[k][4] = iou_gt;
        s_wdata[k][5] = cls;
      }
    }
  }
  __syncthreads();

  // ---- per-cell precompute ----
  float xs[CELLS_PER_T], ys[CELLS_PER_T], cs[CELLS_PER_T];
  float plx[CELLS_PER_T], phx[CELLS_PER_T], ply[CELLS_PER_T], phy[CELLS_PER_T];
  float ap[CELLS_PER_T], msc[CELLS_PER_T];
#pragma unroll
  for (int q = 0; q < CELLS_PER_T; ++q) {
    xs[q] = fsig(v0[q]);
    ys[q] = fsig(v1[q]);
    cs[q] = fsig(v4[q]);
    float pw = fexp(v2[q]) * paw[q], ph = fexp(v3[q]) * pah[q];
    float px = xs[q] + fi[q], py = ys[q] + fj[q];
    plx[q] = px - pw * 0.5f; phx[q] = px + pw * 0.5f;
    ply[q] = py - ph * 0.5f; phy[q] = py + ph * 0.5f;
    ap[q] = 0.375f * (pw * ph);
    msc[q] = -1e30f;
  }

  // ---- suppression: max_iou>0.6 <=> max_t(max(cw,0)*ch - 0.375*Ag_t) > 0.375*Ap ----
#pragma unroll
  for (int c0 = 0; c0 < MAX_BOXES; c0 += 10) {
    float4 bl[10]; float bag[10];
#pragma unroll
    for (int u = 0; u < 10; ++u) { bl[u] = sb_lo[c0 + u]; bag[u] = sb_ag[c0 + u]; }
#pragma unroll
    for (int u = 0; u < 10; ++u) {
#pragma unroll
      for (int q = 0; q < CELLS_PER_T; ++q) {
        float cw = fminf(phx[q], bl[u].y) - fmaxf(plx[q], bl[u].x);
        float ch = fminf(phy[q], bl[u].w) - fmaxf(ply[q], bl[u].z);
        cw = fmaxf(cw, 0.f);
        msc[q] = fmaxf(msc[q], fmaf(cw, ch, -bag[u]));
      }
    }
  }

  // ---- epilogue ----
  int cnt = s_wcnt;
  float acc = 0.f;
#pragma unroll
  for (int q = 0; q < CELLS_PER_T; ++q) {
    if (!ok[q]) continue;
    float cmask = (msc[q] > ap[q]) ? 0.f : NOOBJECT_SCALE;
    float tx = 0.5f, ty = 0.5f, tw = 0.f, th = 0.f, tconf = 0.f, clsloss = 0.f;
    for (int k = 0; k < cnt; ++k) {
      if (s_wcell[k] == sC[q]) {
        cmask = OBJECT_SCALE;
        tx = s_wdata[k][0]; ty = s_wdata[k][1];
        tw = s_wdata[k][2]; th = s_wdata[k][3];
        tconf = s_wdata[k][4];
        int label = (int)s_wdata[k][5];
        const float* cb = basep[q] + 5 * SPAT;
        float m = -1e30f, lv = 0.f;
        for (int c = 0; c < NC; ++c) {
          float vv = cb[c * SPAT];
          if (c == label) lv = vv;
          m = fmaxf(m, vv);
        }
        float ssum = 0.f;
        for (int c = 0; c < NC; ++c) ssum += fexp(cb[c * SPAT] - m);
        clsloss = (m + flog(ssum)) - lv;   // -log_softmax[label]
      }
    }
    float dx = xs[q] - tx, dy = ys[q] - ty, dw = v2[q] - tw, dh = v3[q] - th;
    float dc = cs[q] - tconf;
    acc += 0.5f * (dx * dx + dy * dy + dw * dw + dh * dh + cmask * (dc * dc)) + clsloss;
  }

  // ---- block reduction; per-block partial store (NO global atomic) ----
  for (int o = 32; o > 0; o >>= 1) acc += __shfl_down(acc, o, 64);
  int wid = tid >> 6, lane = tid & 63;
  if (lane == 0) s_red[wid] = acc;
  __syncthreads();
  if (tid == 0) {
    float v = 0.f;
#pragma unroll
    for (int wdx = 0; wdx < TPB / 64; ++wdx) v += s_red[wdx];
    partials[blockIdx.y * GX + blockIdx.x] = v;
  }
}

__global__ __launch_bounds__(256) void reduce_kernel(
    const float* __restrict__ partials, int n, float* __restrict__ outv) {
  float acc = 0.f;
  for (int i = threadIdx.x; i < n; i += 256) acc += partials[i];
  for (int o = 32; o > 0; o >>= 1) acc += __shfl_down(acc, o, 64);
  __shared__ float s_red[4];
  int wid = threadIdx.x >> 6, lane = threadIdx.x & 63;
  if (lane == 0) s_red[wid] = acc;
  __syncthreads();
  if (threadIdx.x == 0) outv[0] = s_red[0] + s_red[1] + s_red[2] + s_red[3];
}

extern "C" void kernel_launch(void* const* d_in, const int* in_sizes, int n_in,
                              void* d_out, int out_size, void* d_ws, size_t ws_size,
                              hipStream_t stream) {
  const float* out = (const float*)d_in[0];
  const float* target = (const float*)d_in[1];
  int nB = in_sizes[0] / (NA * (5 + NC) * SPAT);
  float* partials = (float*)d_ws;   // GX*nB floats, each written unconditionally
  hipLaunchKernelGGL(region_loss_kernel, dim3(GX, nB), dim3(TPB), 0, stream,
                     out, target, partials);
  hipLaunchKernelGGL(reduce_kernel, dim3(1), dim3(256), 0, stream,
                     partials, GX * nB, (float*)d_out);
}

// Round 6
// 104.715 us; speedup vs baseline: 1.1305x; 1.1305x over previous
//
#include <hip/hip_runtime.h>
#include <math.h>

#define NA 5
#define NC 20
#define NH 38
#define NW 38
#define MAX_BOXES 50
#define SPAT (NH * NW)            // 1444
#define CELLS_PER_B (NA * SPAT)   // 7220
#define TPB 256
#define CELLS_PER_T 2
#define CPB (TPB * CELLS_PER_T)   // 512
#define GX ((CELLS_PER_B + CPB - 1) / CPB)  // 15
#define OBJECT_SCALE 5.0f
#define NOOBJECT_SCALE 1.0f

__constant__ float c_aw[NA]  = {1.3221f, 3.19275f, 5.05587f, 9.47112f, 11.2364f};
__constant__ float c_ah[NA]  = {1.73145f, 4.00944f, 8.09892f, 4.84053f, 10.0071f};
__constant__ float c_iaw[NA] = {1.f/1.3221f, 1.f/3.19275f, 1.f/5.05587f, 1.f/9.47112f, 1.f/11.2364f};
__constant__ float c_iah[NA] = {1.f/1.73145f, 1.f/4.00944f, 1.f/8.09892f, 1.f/4.84053f, 1.f/10.0071f};

__device__ __forceinline__ float fexp(float v) { return __expf(v); }
__device__ __forceinline__ float flog(float v) { return __logf(v); }
__device__ __forceinline__ float frcp(float v) { return __builtin_amdgcn_rcpf(v); }
__device__ __forceinline__ float fsig(float v) { return frcp(1.f + __expf(-v)); }

__device__ __forceinline__ float iou_fast(float x1, float y1, float w1, float h1,
                                          float x2, float y2, float w2, float h2) {
  float uw = fmaxf(x1 + w1 * 0.5f, x2 + w2 * 0.5f) - fminf(x1 - w1 * 0.5f, x2 - w2 * 0.5f);
  float uh = fmaxf(y1 + h1 * 0.5f, y2 + h2 * 0.5f) - fminf(y1 - h1 * 0.5f, y2 - h2 * 0.5f);
  float cw = w1 + w2 - uw;
  float ch = h1 + h2 - uh;
  float inter = (cw <= 0.f || ch <= 0.f) ? 0.f : cw * ch;
  return inter * frcp(w1 * h1 + w2 * h2 - inter);
}

// exact divide for the anchor argmax (discrete decision -> keep exact)
__device__ __forceinline__ float iou_wh_exact(float w1, float h1, float w2, float h2) {
  float uw = fmaxf(w1 * 0.5f, w2 * 0.5f) - fminf(-w1 * 0.5f, -w2 * 0.5f);
  float uh = fmaxf(h1 * 0.5f, h2 * 0.5f) - fminf(-h1 * 0.5f, -h2 * 0.5f);
  float cw = w1 + w2 - uw;
  float ch = h1 + h2 - uh;
  float inter = (cw <= 0.f || ch <= 0.f) ? 0.f : cw * ch;
  return inter / (w1 * h1 + w2 * h2 - inter);
}

// ---------- K1: per-batch prep. Grid (nB), 64 threads (1 wave). ----------
// Computes the 50 suppression boxes (to global for K2) AND, for each winner
// box, the full loss DELTA (winner terms minus the default terms the main
// kernel will compute at that cell), including the class CE. Main kernel
// then needs zero winner logic.
__global__ __launch_bounds__(64) void prep_kernel(
    const float* __restrict__ out, const float* __restrict__ target,
    float4* __restrict__ boxes, float* __restrict__ delta) {
  const int b = blockIdx.x;
  const int t = threadIdx.x;
  __shared__ float4 sb_lo[MAX_BOXES];
  __shared__ float  sb_ag[MAX_BOXES];

  float cls = 0.f, x = 0.f, y = 0.f, w = 0.f, h = 0.f;
  if (t < MAX_BOXES) {
    const float* tg = target + (size_t)(b * MAX_BOXES + t) * 5;
    cls = tg[0]; x = tg[1]; y = tg[2]; w = tg[3]; h = tg[4];
  }
  unsigned long long nz = __ballot(t < MAX_BOXES && x != 0.f);
  unsigned long long low = (t < 63) ? ((1ull << (t + 1)) - 1ull) : ~0ull;
  bool valid = (t < MAX_BOXES) && ((nz & low) == low);

  float gx = x * NW, gy = y * NH, gw = w * NW, gh = h * NH;

  int best = 0; float bestiou = -1.f;
#pragma unroll
  for (int a2 = 0; a2 < NA; ++a2) {
    float aiou = iou_wh_exact(gw, gh, c_aw[a2], c_ah[a2]);
    if (aiou > bestiou) { bestiou = aiou; best = a2; }
  }
  int gi = min(max((int)gx, 0), NW - 1);
  int gj = min(max((int)gy, 0), NH - 1);
  int cell = best * SPAT + gj * NW + gi;

  unsigned long long vm = __ballot(valid);
  bool winner = valid;                       // last valid writer to a cell wins
  for (int tp = 0; tp < MAX_BOXES; ++tp) {
    int c2 = __shfl(cell, tp);
    if (tp > t && ((vm >> tp) & 1ull) && c2 == cell) winner = false;
  }

  float4 lo; float ag;
  if (valid) {
    lo = make_float4(gx - gw * 0.5f, gx + gw * 0.5f, gy - gh * 0.5f, gy + gh * 0.5f);
    ag = 0.375f * (gw * gh);
  } else {
    lo = make_float4(1e30f, 1e30f, 1e30f, 1e30f);   // cw<0 after clamp: never suppresses
    ag = 0.f;
  }
  if (t < MAX_BOXES) {
    boxes[(size_t)(b * MAX_BOXES + t) * 2]     = lo;
    boxes[(size_t)(b * MAX_BOXES + t) * 2 + 1] = make_float4(ag, 0.f, 0.f, 0.f);
    sb_lo[t] = lo;
    sb_ag[t] = ag;
  }
  __syncthreads();

  float d = 0.f;
  if (winner) {
    const float* bp = out + ((size_t)(b * NA + best) * 25) * SPAT + gj * NW + gi;
    float v0 = bp[0], v1 = bp[SPAT], v2 = bp[2 * SPAT], v3 = bp[3 * SPAT], v4 = bp[4 * SPAT];
    float xs = fsig(v0), ys = fsig(v1), cs = fsig(v4);
    float pw = fexp(v2) * c_aw[best], ph = fexp(v3) * c_ah[best];
    float px = xs + (float)gi, py = ys + (float)gj;
    float plx = px - pw * 0.5f, phx = px + pw * 0.5f;
    float ply = py - ph * 0.5f, phy = py + ph * 0.5f;
    float ap = 0.375f * (pw * ph);

    // replicate main kernel's default path at this cell
    float msc = -1e30f;
    for (int t2 = 0; t2 < MAX_BOXES; ++t2) {
      float4 l2 = sb_lo[t2];
      float cw = fminf(phx, l2.y) - fmaxf(plx, l2.x);
      float ch = fminf(phy, l2.w) - fmaxf(ply, l2.z);
      cw = fmaxf(cw, 0.f);
      msc = fmaxf(msc, fmaf(cw, ch, -sb_ag[t2]));
    }
    float cmask_def = (msc > ap) ? 0.f : NOOBJECT_SCALE;
    float xd = xs - 0.5f, yd = ys - 0.5f;
    float D = 0.5f * (xd * xd + yd * yd + v2 * v2 + v3 * v3 + cmask_def * (cs * cs));

    // winner terms
    float txv = gx - (float)gi, tyv = gy - (float)gj;
    float twv = flog(gw * c_iaw[best]), thv = flog(gh * c_iah[best]);
    float tconf = iou_fast(gx, gy, gw, gh, px, py, pw, ph);
    float dx = xs - txv, dy = ys - tyv, dwv = v2 - twv, dhv = v3 - thv, dc = cs - tconf;

    int label = (int)cls;
    const float* cb = bp + 5 * SPAT;
    float m = -1e30f, lv = 0.f;
    for (int c = 0; c < NC; ++c) {
      float vv = cb[c * SPAT];
      if (c == label) lv = vv;
      m = fmaxf(m, vv);
    }
    float ssum = 0.f;
    for (int c = 0; c < NC; ++c) ssum += fexp(cb[c * SPAT] - m);
    float ce = (m + flog(ssum)) - lv;       // -log_softmax[label]

    float W = 0.5f * (dx * dx + dy * dy + dwv * dwv + dhv * dhv +
                      OBJECT_SCALE * (dc * dc)) + ce;
    d = W - D;
  }
  for (int o = 32; o > 0; o >>= 1) d += __shfl_down(d, o, 64);
  if (t == 0) delta[b] = d;
}

// ---------- K2: default loss, fully regular, no divergence. ----------
// Grid (15, nB), 256 threads, 2 cells/thread. Boxes staged global->LDS by
// threads 0..49 BEFORE any per-cell loads (so the barrier drains ~nothing).
__global__ __launch_bounds__(TPB) void main_kernel(
    const float* __restrict__ out, const float4* __restrict__ boxes,
    float* __restrict__ partials) {
  const int b = blockIdx.y;
  const int s0 = blockIdx.x * CPB;
  const int tid = threadIdx.x;

  __shared__ float4 sb_lo[MAX_BOXES];
  __shared__ float  sb_ag[MAX_BOXES];
  __shared__ float  s_red[TPB / 64];

  if (tid < MAX_BOXES) {
    float4 lo = boxes[(size_t)(b * MAX_BOXES + tid) * 2];
    float4 hi = boxes[(size_t)(b * MAX_BOXES + tid) * 2 + 1];
    sb_lo[tid] = lo;
    sb_ag[tid] = hi.x;
  }
  __syncthreads();

  bool ok[CELLS_PER_T];
  float v0[CELLS_PER_T], v1[CELLS_PER_T], v2[CELLS_PER_T], v3[CELLS_PER_T], v4[CELLS_PER_T];
  float fi[CELLS_PER_T], fj[CELLS_PER_T], paw[CELLS_PER_T], pah[CELLS_PER_T];
#pragma unroll
  for (int q = 0; q < CELLS_PER_T; ++q) {
    int s = s0 + q * TPB + tid;
    ok[q] = (s < CELLS_PER_B);
    int sc = ok[q] ? s : 0;
    unsigned a = (unsigned)sc / SPAT;
    unsigned r = (unsigned)sc - a * SPAT;
    unsigned j = r / NW, i = r - j * NW;
    fi[q] = (float)i; fj[q] = (float)j;
    paw[q] = c_aw[a]; pah[q] = c_ah[a];
    const float* bp = out + ((size_t)(b * NA + a) * 25) * SPAT + r;
    v0[q] = bp[0];
    v1[q] = bp[SPAT];
    v2[q] = bp[2 * SPAT];
    v3[q] = bp[3 * SPAT];
    v4[q] = bp[4 * SPAT];
  }

  float xs[CELLS_PER_T], ys[CELLS_PER_T], cs[CELLS_PER_T];
  float plx[CELLS_PER_T], phx[CELLS_PER_T], ply[CELLS_PER_T], phy[CELLS_PER_T];
  float ap[CELLS_PER_T], msc[CELLS_PER_T];
#pragma unroll
  for (int q = 0; q < CELLS_PER_T; ++q) {
    xs[q] = fsig(v0[q]);
    ys[q] = fsig(v1[q]);
    cs[q] = fsig(v4[q]);
    float pw = fexp(v2[q]) * paw[q], ph = fexp(v3[q]) * pah[q];
    float px = xs[q] + fi[q], py = ys[q] + fj[q];
    plx[q] = px - pw * 0.5f; phx[q] = px + pw * 0.5f;
    ply[q] = py - ph * 0.5f; phy[q] = py + ph * 0.5f;
    ap[q] = 0.375f * (pw * ph);
    msc[q] = -1e30f;
  }

  // suppression: max_iou>0.6  <=>  max_t( max(cw,0)*ch - 0.375*Ag_t ) > 0.375*Ap
#pragma unroll
  for (int c0 = 0; c0 < MAX_BOXES; c0 += 10) {
    float4 bl[10]; float bag[10];
#pragma unroll
    for (int u = 0; u < 10; ++u) { bl[u] = sb_lo[c0 + u]; bag[u] = sb_ag[c0 + u]; }
#pragma unroll
    for (int u = 0; u < 10; ++u) {
#pragma unroll
      for (int q = 0; q < CELLS_PER_T; ++q) {
        float cw = fminf(phx[q], bl[u].y) - fmaxf(plx[q], bl[u].x);
        float ch = fminf(phy[q], bl[u].w) - fmaxf(ply[q], bl[u].z);
        cw = fmaxf(cw, 0.f);
        msc[q] = fmaxf(msc[q], fmaf(cw, ch, -bag[u]));
      }
    }
  }

  float acc = 0.f;
#pragma unroll
  for (int q = 0; q < CELLS_PER_T; ++q) {
    if (!ok[q]) continue;
    float cmask = (msc[q] > ap[q]) ? 0.f : NOOBJECT_SCALE;
    float xd = xs[q] - 0.5f, yd = ys[q] - 0.5f;
    acc += 0.5f * (xd * xd + yd * yd + v2[q] * v2[q] + v3[q] * v3[q] +
                   cmask * (cs[q] * cs[q]));
  }

  for (int o = 32; o > 0; o >>= 1) acc += __shfl_down(acc, o, 64);
  int wid = tid >> 6, lane = tid & 63;
  if (lane == 0) s_red[wid] = acc;
  __syncthreads();
  if (tid == 0) {
    float v = 0.f;
#pragma unroll
    for (int wdx = 0; wdx < TPB / 64; ++wdx) v += s_red[wdx];
    partials[blockIdx.y * GX + blockIdx.x] = v;
  }
}

// ---------- K3: final reduce over partials (960) + deltas (64), contiguous. ----------
__global__ __launch_bounds__(256) void reduce_kernel(
    const float* __restrict__ vals, int n, float* __restrict__ outv) {
  float acc = 0.f;
  for (int i = threadIdx.x; i < n; i += 256) acc += vals[i];
  for (int o = 32; o > 0; o >>= 1) acc += __shfl_down(acc, o, 64);
  __shared__ float s_red[4];
  int wid = threadIdx.x >> 6, lane = threadIdx.x & 63;
  if (lane == 0) s_red[wid] = acc;
  __syncthreads();
  if (threadIdx.x == 0) outv[0] = s_red[0] + s_red[1] + s_red[2] + s_red[3];
}

extern "C" void kernel_launch(void* const* d_in, const int* in_sizes, int n_in,
                              void* d_out, int out_size, void* d_ws, size_t ws_size,
                              hipStream_t stream) {
  const float* out = (const float*)d_in[0];
  const float* target = (const float*)d_in[1];
  int nB = in_sizes[0] / (NA * (5 + NC) * SPAT);

  // ws layout: boxes | partials | delta  (partials+delta contiguous for K3)
  float4* boxes = (float4*)d_ws;                                   // nB*50*2 float4
  float* partials = (float*)((char*)d_ws + (size_t)nB * MAX_BOXES * 2 * sizeof(float4));
  float* delta = partials + GX * nB;

  hipLaunchKernelGGL(prep_kernel, dim3(nB), dim3(64), 0, stream,
                     out, target, boxes, delta);
  hipLaunchKernelGGL(main_kernel, dim3(GX, nB), dim3(TPB), 0, stream,
                     out, boxes, partials);
  hipLaunchKernelGGL(reduce_kernel, dim3(1), dim3(256), 0, stream,
                     partials, GX * nB + nB, (float*)d_out);
}